// Round 2
// baseline (1276.401 us; speedup 1.0000x reference)
//
#include <hip/hip_runtime.h>
#include <hip/hip_bf16.h>
#include <stdint.h>

// Problem constants: B=4, C=192, H=W=224, WS=8, NH=6, hd=32, SHIFT=4
// I/O dtype: float32 (per reference). Internal compute: bf16 MFMA, fp32 acc.
#define HHW   224
#define CCH   192
#define NHEAD 6
#define SHIFT 4
#define NWIN  3136           // 4 * 28 * 28
#define QN    38535168ull    // 3136*6*64*32 elements per Q/K/V tensor (bf16)

typedef __attribute__((ext_vector_type(8))) short bf16x8;   // MFMA A/B frag (4 VGPRs)
typedef __attribute__((ext_vector_type(4))) float f32x4;    // MFMA C/D frag

__device__ __forceinline__ ushort f2bf(float f) {
    union { float f; uint32_t i; } v; v.f = f;
    uint32_t u = v.i;
    return (ushort)((u + 0x7FFFu + ((u >> 16) & 1u)) >> 16);  // RNE
}

// ---------------------------------------------------------------------------
// C^T-form windowed GEMM: out[o][t] = bias[o] + sum_c W[o][c] * x[t][c]
// One block per window (64 tokens). OCH=576 -> QKV (writes bf16 Q,K,V^T to ws),
// OCH=192 -> proj (reads attn fp32 from dout, writes proj fp32 to dout
// IN-PLACE; safe: all global reads complete before the first __syncthreads
// [the barrier drains vmcnt], and windows' read/write sets are identical &
// disjoint across blocks). Roll(+SHIFT) folded into x stage and proj store.
// ---------------------------------------------------------------------------
template<int OCH>
__global__ __launch_bounds__(256, 2) void gemm_win(
    const float* xin, const float* __restrict__ wgt,
    const float* __restrict__ bias,
    ushort* __restrict__ qo, ushort* __restrict__ ko, ushort* __restrict__ vto,
    float* dout)
{
    // +8 pad: row stride 400 B (16B-aligned), 2-way bank aliasing on frag
    // reads (free on CDNA4).
    __shared__ ushort xt[64][200];   // x tile, [token][channel], bf16
    __shared__ ushort wc[96][200];   // weight chunk, [o][channel], bf16

    const int tid = threadIdx.x;
    const int win = blockIdx.x;
    const int b = win / 784, hn = (win / 28) % 28, wn = win % 28;
    const float* xbase = xin + (size_t)b * CCH * HHW * HHW;

    // Stage x tile with transpose (global is channel-major) + roll fold + cvt.
    for (int u = tid; u < CCH * 64; u += 256) {
        int c = u >> 6, t = u & 63;
        int hh = (hn * 8 + (t >> 3) + SHIFT) % HHW;
        int ww = (wn * 8 + (t & 7) + SHIFT) % HHW;
        xt[t][c] = f2bf(xbase[((size_t)c * HHW + hh) * HHW + ww]);
    }

    const int wave = tid >> 6, lane = tid & 63;
    const int quad = lane >> 4, l16 = lane & 15;
    const int t_n = wave * 16 + l16;   // this wave owns N-tile = wave (16 tokens)

    for (int ch = 0; ch < OCH / 96; ch++) {
        const int obase = ch * 96;
        // Stage 96 weight rows: float4 global loads -> 4x bf16 LDS stores.
        for (int u = tid; u < 96 * 48; u += 256) {
            int oo = u / 48, c4 = (u % 48) * 4;
            float4 w4 = *(const float4*)(wgt + (size_t)(obase + oo) * CCH + c4);
            wc[oo][c4 + 0] = f2bf(w4.x);
            wc[oo][c4 + 1] = f2bf(w4.y);
            wc[oo][c4 + 2] = f2bf(w4.z);
            wc[oo][c4 + 3] = f2bf(w4.w);
        }
        __syncthreads();

        f32x4 acc[6];
        #pragma unroll
        for (int m = 0; m < 6; m++) acc[m] = (f32x4){0.f, 0.f, 0.f, 0.f};
        #pragma unroll
        for (int k = 0; k < 6; k++) {   // K = 192 = 6 * 32
            bf16x8 bfrag = *(const bf16x8*)&xt[t_n][k * 32 + quad * 8];
            #pragma unroll
            for (int m = 0; m < 6; m++) {
                bf16x8 afrag = *(const bf16x8*)&wc[m * 16 + l16][k * 32 + quad * 8];
                acc[m] = __builtin_amdgcn_mfma_f32_16x16x32_bf16(afrag, bfrag, acc[m], 0, 0, 0);
            }
        }
        // Epilogue: D row = o_local = quad*4+reg, col = token = l16 (+wave*16).
        #pragma unroll
        for (int m = 0; m < 6; m++) {
            #pragma unroll
            for (int rg = 0; rg < 4; rg++) {
                int o = obase + m * 16 + quad * 4 + rg;
                float val = acc[m][rg] + bias[o];
                if (OCH == 576) {
                    ushort bv = f2bf(val);
                    int s = o / 192, rem = o % 192;
                    int h = rem >> 5, d = rem & 31;
                    size_t wh = (size_t)(win * NHEAD + h);
                    if (s == 0)      qo[(wh * 64 + t_n) * 32 + d] = bv;  // Q [t][d]
                    else if (s == 1) ko[(wh * 64 + t_n) * 32 + d] = bv;  // K [t][d]
                    else             vto[(wh * 32 + d) * 64 + t_n] = bv; // V^T [d][t]
                } else {
                    int hh = (hn * 8 + (t_n >> 3) + SHIFT) % HHW;
                    int ww = (wn * 8 + (t_n & 7) + SHIFT) % HHW;
                    dout[(((size_t)b * CCH + o) * HHW + hh) * HHW + ww] = val;
                }
            }
        }
        __syncthreads();   // protect wc before next chunk's staging
    }
}

// ---------------------------------------------------------------------------
// Attention: one wave per (window, head). QK^T (16 MFMA, K=32=hd) ->
// in-register softmax (quad-local shfl_xor reduce) -> P through LDS
// (C-layout -> A-layout transform) -> PV (16 MFMA) -> fp32 scatter store to
// d_out at rolled coords (proj kernel reads them back with the same fold).
// ---------------------------------------------------------------------------
__global__ __launch_bounds__(256, 2) void attn_win(
    const ushort* __restrict__ q, const ushort* __restrict__ k,
    const ushort* __restrict__ vt, float* __restrict__ dout)
{
    __shared__ ushort pt[4][64][72];   // P per wave; +8 pad

    const int tid = threadIdx.x;
    const int wave = tid >> 6, lane = tid & 63;
    const int quad = lane >> 4, l16 = lane & 15;
    const int task = blockIdx.x * 4 + wave;      // 18816 = 4704 * 4 exactly
    const int win = task / 6, h = task % 6;
    const int b = win / 784, hn = (win / 28) % 28, wn = win % 28;

    const ushort* qp = q  + (size_t)(win * 6 + h) * 2048;
    const ushort* kp = k  + (size_t)(win * 6 + h) * 2048;
    const ushort* vp = vt + (size_t)(win * 6 + h) * 2048;

    // QK^T: A frag = Q[m=l16][d=quad*8+j], B frag = K[n=l16][d=quad*8+j]
    f32x4 s[4][4];
    #pragma unroll
    for (int mt = 0; mt < 4; mt++)
        #pragma unroll
        for (int nt = 0; nt < 4; nt++) s[mt][nt] = (f32x4){0.f, 0.f, 0.f, 0.f};

    bf16x8 qf[4], kf[4];
    #pragma unroll
    for (int mt = 0; mt < 4; mt++) qf[mt] = *(const bf16x8*)&qp[(mt * 16 + l16) * 32 + quad * 8];
    #pragma unroll
    for (int nt = 0; nt < 4; nt++) kf[nt] = *(const bf16x8*)&kp[(nt * 16 + l16) * 32 + quad * 8];
    #pragma unroll
    for (int mt = 0; mt < 4; mt++)
        #pragma unroll
        for (int nt = 0; nt < 4; nt++)
            s[mt][nt] = __builtin_amdgcn_mfma_f32_16x16x32_bf16(qf[mt], kf[nt], s[mt][nt], 0, 0, 0);

    // Softmax per Q-row (row = mt*16 + quad*4 + rg; its 64 cols live in this
    // quad's 16 lanes x 4 N-tiles). scale*log2(e) folded into exp2.
    const float SC = 0.25506953149031837f;   // (1/sqrt(32)) * log2(e)
    #pragma unroll
    for (int mt = 0; mt < 4; mt++) {
        #pragma unroll
        for (int rg = 0; rg < 4; rg++) {
            float v0 = s[mt][0][rg], v1 = s[mt][1][rg], v2 = s[mt][2][rg], v3 = s[mt][3][rg];
            float mx = fmaxf(fmaxf(v0, v1), fmaxf(v2, v3));
            #pragma unroll
            for (int msk = 1; msk < 16; msk <<= 1) mx = fmaxf(mx, __shfl_xor(mx, msk, 64));
            float e0 = exp2f((v0 - mx) * SC), e1 = exp2f((v1 - mx) * SC);
            float e2 = exp2f((v2 - mx) * SC), e3 = exp2f((v3 - mx) * SC);
            float sm = (e0 + e1) + (e2 + e3);
            #pragma unroll
            for (int msk = 1; msk < 16; msk <<= 1) sm += __shfl_xor(sm, msk, 64);
            float r = __builtin_amdgcn_rcpf(sm);
            int qt = mt * 16 + quad * 4 + rg;
            pt[wave][qt][ 0 + l16] = f2bf(e0 * r);
            pt[wave][qt][16 + l16] = f2bf(e1 * r);
            pt[wave][qt][32 + l16] = f2bf(e2 * r);
            pt[wave][qt][48 + l16] = f2bf(e3 * r);
        }
    }
    __syncthreads();   // uniform; orders pt writes vs frag reads

    // PV: A = P[qt][kt] from LDS, B = V^T[d][kt] (contiguous 16B per lane)
    f32x4 o[4][2];
    #pragma unroll
    for (int mt = 0; mt < 4; mt++)
        #pragma unroll
        for (int nt = 0; nt < 2; nt++) o[mt][nt] = (f32x4){0.f, 0.f, 0.f, 0.f};
    #pragma unroll
    for (int ks = 0; ks < 2; ks++) {   // K = 64 tokens = 2 * 32
        bf16x8 vf[2];
        #pragma unroll
        for (int nt = 0; nt < 2; nt++)
            vf[nt] = *(const bf16x8*)&vp[(nt * 16 + l16) * 64 + ks * 32 + quad * 8];
        #pragma unroll
        for (int mt = 0; mt < 4; mt++) {
            bf16x8 pf = *(const bf16x8*)&pt[wave][mt * 16 + l16][ks * 32 + quad * 8];
            #pragma unroll
            for (int nt = 0; nt < 2; nt++)
                o[mt][nt] = __builtin_amdgcn_mfma_f32_16x16x32_bf16(pf, vf[nt], o[mt][nt], 0, 0, 0);
        }
    }

    // Store attn output (fp32) at rolled coords (channel cc = h*32 + d).
    const size_t ob = (size_t)b * CCH;
    #pragma unroll
    for (int mt = 0; mt < 4; mt++) {
        #pragma unroll
        for (int nt = 0; nt < 2; nt++) {
            #pragma unroll
            for (int rg = 0; rg < 4; rg++) {
                int qt = mt * 16 + quad * 4 + rg;
                int cc = h * 32 + nt * 16 + l16;
                int hh = (hn * 8 + (qt >> 3) + SHIFT) % HHW;
                int ww = (wn * 8 + (qt & 7) + SHIFT) % HHW;
                dout[((ob + cc) * HHW + hh) * HHW + ww] = o[mt][nt][rg];
            }
        }
    }
}

extern "C" void kernel_launch(void* const* d_in, const int* in_sizes, int n_in,
                              void* d_out, int out_size, void* d_ws, size_t ws_size,
                              hipStream_t stream) {
    const float* x      = (const float*)d_in[0];
    const float* w_qkv  = (const float*)d_in[1];
    const float* b_qkv  = (const float*)d_in[2];
    const float* w_proj = (const float*)d_in[3];
    const float* b_proj = (const float*)d_in[4];
    float* out = (float*)d_out;
    ushort* ws = (ushort*)d_ws;

    ushort* Q  = ws;            // [win][h][64][32] bf16
    ushort* K  = ws + QN;       // [win][h][64][32] bf16
    ushort* VT = ws + 2 * QN;   // [win][h][32][64] bf16  (total 231 MB)

    gemm_win<576><<<NWIN, 256, 0, stream>>>(x, w_qkv, b_qkv, Q, K, VT, nullptr);
    attn_win<<<4704, 256, 0, stream>>>(Q, K, VT, out);
    gemm_win<192><<<NWIN, 256, 0, stream>>>(out, w_proj, b_proj, nullptr, nullptr, nullptr, out);
}

// Round 3
// 748.683 us; speedup vs baseline: 1.7049x; 1.7049x over previous
//
#include <hip/hip_runtime.h>
#include <stdint.h>

// B=4, C=192, H=W=224, WS=8, NH=6, hd=32, SHIFT=4. I/O fp32; internal bf16 MFMA.
#define HHW   224
#define CCH   192
#define SHIFT 4
#define NWIN  3136           // 4 * 28 * 28
#define NTOK  200704         // NWIN * 64
#define QN    38535168ull    // NWIN*6*64*32 elements per Q/K/VT tensor (bf16)

typedef __attribute__((ext_vector_type(8))) short bf16x8;   // MFMA A/B frag
typedef __attribute__((ext_vector_type(4))) float f32x4;    // MFMA C/D frag

__device__ __forceinline__ ushort f2bf(float f) {
    union { float f; uint32_t i; } v; v.f = f;
    uint32_t u = v.i;
    return (ushort)((u + 0x7FFFu + ((u >> 16) & 1u)) >> 16);  // RNE
}

// ---------------------------------------------------------------------------
// prep: x fp32 [b][c][h][w] -> X1 bf16 [p][c], p = win*64 + t, roll(+4) folded.
// SHIFT=4 guarantees every 4-pixel token run is a contiguous aligned float4
// even across the %224 wrap. LDS transpose -> fully coalesced uint4 out.
// ---------------------------------------------------------------------------
__global__ __launch_bounds__(256) void prep_x(const float* __restrict__ x,
                                              ushort* __restrict__ xo)
{
    __shared__ ushort xt[64][200];   // +8 pad
    const int win = blockIdx.x;
    const int b = win / 784, hn = (win / 28) % 28, wn = win % 28;
    const float* xb = x + (size_t)b * CCH * HHW * HHW;

    for (int u = threadIdx.x; u < CCH * 16; u += 256) {
        int c = u >> 4, r = u & 15;
        int t0 = r * 4;                       // tokens t0..t0+3: same row-of-8
        int hh = (hn * 8 + (t0 >> 3) + SHIFT) % HHW;
        int ww = (wn * 8 + (t0 & 7) + SHIFT) % HHW;   // %4==0, wrap-safe
        float4 v = *(const float4*)(xb + ((size_t)c * HHW + hh) * HHW + ww);
        xt[t0 + 0][c] = f2bf(v.x); xt[t0 + 1][c] = f2bf(v.y);
        xt[t0 + 2][c] = f2bf(v.z); xt[t0 + 3][c] = f2bf(v.w);
    }
    __syncthreads();
    ushort* xw = xo + (size_t)win * 12288;
    for (int u = threadIdx.x; u < 64 * 24; u += 256) {
        int t = u / 24, c8 = u % 24;
        *(uint4*)(xw + t * 192 + c8 * 8) = *(const uint4*)&xt[t][c8 * 8];
    }
}

// ---------------------------------------------------------------------------
// GEMM: out[o][p] = bias[o] + sum_c W[o][c] * X1[p][c].  N=128 tokens/block,
// wave owns 32 tokens (2 n-frags); B-frags loaded ONCE directly from global
// (16B/lane, 64B-line groups, each element read exactly once). A = weights,
// staged fp32->bf16 per 96-row chunk into padded LDS (2-way-free b128 reads).
// OCH=576: packed uint2 Q/K stores + V^T scatter.  OCH=192: fp32 out scatter
// with roll fold.
// ---------------------------------------------------------------------------
template<int OCH>
__global__ __launch_bounds__(256, 3) void gemm_win(
    const ushort* __restrict__ xin, const float* __restrict__ wgt,
    const float* __restrict__ bias,
    ushort* __restrict__ qo, ushort* __restrict__ ko, ushort* __restrict__ vto,
    float* __restrict__ dout)
{
    __shared__ ushort wc[96][200];   // weight chunk bf16, +8 pad
    __shared__ float  bs[OCH];

    const int tid = threadIdx.x;
    const int wave = tid >> 6, lane = tid & 63;
    const int quad = lane >> 4, l16 = lane & 15;
    const int p0 = blockIdx.x * 128 + wave * 32;

    for (int u = tid; u < OCH; u += 256) bs[u] = bias[u];

    // B-frags: all 192 channels of this wave's 32 tokens, held in VGPRs.
    bf16x8 bfr[2][6];
    #pragma unroll
    for (int nt = 0; nt < 2; nt++)
        #pragma unroll
        for (int k = 0; k < 6; k++)
            bfr[nt][k] = *(const bf16x8*)(xin + (size_t)(p0 + nt * 16 + l16) * CCH + k * 32 + quad * 8);

    #pragma unroll
    for (int ch = 0; ch < OCH / 96; ch++) {
        const int obase = ch * 96;
        // Stage 96 weight rows fp32 -> bf16 LDS.
        for (int u = tid; u < 96 * 48; u += 256) {
            int oo = u / 48, c4 = (u % 48) * 4;
            float4 w4 = *(const float4*)(wgt + (size_t)(obase + oo) * CCH + c4);
            wc[oo][c4 + 0] = f2bf(w4.x); wc[oo][c4 + 1] = f2bf(w4.y);
            wc[oo][c4 + 2] = f2bf(w4.z); wc[oo][c4 + 3] = f2bf(w4.w);
        }
        __syncthreads();

        f32x4 acc[6][2];
        #pragma unroll
        for (int m = 0; m < 6; m++)
            #pragma unroll
            for (int nt = 0; nt < 2; nt++) acc[m][nt] = (f32x4){0.f, 0.f, 0.f, 0.f};
        #pragma unroll
        for (int k = 0; k < 6; k++) {
            #pragma unroll
            for (int m = 0; m < 6; m++) {
                bf16x8 afrag = *(const bf16x8*)&wc[m * 16 + l16][k * 32 + quad * 8];
                acc[m][0] = __builtin_amdgcn_mfma_f32_16x16x32_bf16(afrag, bfr[0][k], acc[m][0], 0, 0, 0);
                acc[m][1] = __builtin_amdgcn_mfma_f32_16x16x32_bf16(afrag, bfr[1][k], acc[m][1], 0, 0, 0);
            }
        }
        // Epilogue. D row = quad*4+rg (o dim), col = l16 (token dim).
        #pragma unroll
        for (int m = 0; m < 6; m++) {
            const int o0 = obase + m * 16 + quad * 4;          // %4 == 0
            float4 bb = *(const float4*)&bs[o0];
            #pragma unroll
            for (int nt = 0; nt < 2; nt++) {
                int token = p0 + nt * 16 + l16;
                int win = token >> 6, t = token & 63;
                float f0 = acc[m][nt][0] + bb.x, f1 = acc[m][nt][1] + bb.y;
                float f2 = acc[m][nt][2] + bb.z, f3 = acc[m][nt][3] + bb.w;
                if (OCH == 576) {
                    const int s = o0 / 192;                    // uniform per (ch,m)
                    const int rem = o0 % 192;
                    const int h = rem >> 5, d0 = rem & 31;     // d0 %4 == 0
                    size_t wh = (size_t)win * 6 + h;
                    if (s == 2) {
                        vto[(wh * 32 + d0 + 0) * 64 + t] = f2bf(f0);
                        vto[(wh * 32 + d0 + 1) * 64 + t] = f2bf(f1);
                        vto[(wh * 32 + d0 + 2) * 64 + t] = f2bf(f2);
                        vto[(wh * 32 + d0 + 3) * 64 + t] = f2bf(f3);
                    } else {
                        uint2 pk;
                        pk.x = (uint32_t)f2bf(f0) | ((uint32_t)f2bf(f1) << 16);
                        pk.y = (uint32_t)f2bf(f2) | ((uint32_t)f2bf(f3) << 16);
                        ushort* dst = (s == 0 ? qo : ko) + (wh * 64 + t) * 32 + d0;
                        *(uint2*)dst = pk;
                    }
                } else {
                    int b = win / 784, hn = (win / 28) % 28, wn = win % 28;
                    int hh = (hn * 8 + (t >> 3) + SHIFT) % HHW;
                    int ww = (wn * 8 + (t & 7) + SHIFT) % HHW;
                    float* dst = dout + ((size_t)(b * CCH + o0) * HHW + hh) * HHW + ww;
                    dst[0] = f0; dst[(size_t)HHW * HHW] = f1;
                    dst[2 * (size_t)HHW * HHW] = f2; dst[3 * (size_t)HHW * HHW] = f3;
                }
            }
        }
        __syncthreads();
    }
}

// ---------------------------------------------------------------------------
// attn: one block = one window, 6 waves = 6 heads. QK^T -> softmax -> P via
// LDS -> PV. Output X2 bf16 [t][c] ALIASED onto the Q buffer (same per-window
// 24 KB block). Safe: all Q/K/V frag loads are issued before __syncthreads
// (which drains vmcnt(0)); X2 stores happen strictly after.
// ---------------------------------------------------------------------------
__global__ __launch_bounds__(384, 3) void attn_win(
    ushort* qx2,                                   // Q in / X2 out (aliased)
    const ushort* __restrict__ k, const ushort* __restrict__ vt)
{
    __shared__ ushort pt[6][64][72];

    const int tid = threadIdx.x;
    const int h = tid >> 6, lane = tid & 63;
    const int quad = lane >> 4, l16 = lane & 15;
    const int win = blockIdx.x;

    const ushort* qp = qx2 + (size_t)(win * 6 + h) * 2048;
    const ushort* kp = k   + (size_t)(win * 6 + h) * 2048;
    const ushort* vp = vt  + (size_t)(win * 6 + h) * 2048;

    // Hoist K and V frags (V must be loaded before the barrier for aliasing).
    bf16x8 kf[4], vf[2][2];
    #pragma unroll
    for (int nt = 0; nt < 4; nt++) kf[nt] = *(const bf16x8*)&kp[(nt * 16 + l16) * 32 + quad * 8];
    #pragma unroll
    for (int ks = 0; ks < 2; ks++)
        #pragma unroll
        for (int nt = 0; nt < 2; nt++)
            vf[ks][nt] = *(const bf16x8*)&vp[(nt * 16 + l16) * 64 + ks * 32 + quad * 8];

    f32x4 s[4][4];
    #pragma unroll
    for (int mt = 0; mt < 4; mt++) {
        bf16x8 qf = *(const bf16x8*)&qp[(mt * 16 + l16) * 32 + quad * 8];
        #pragma unroll
        for (int nt = 0; nt < 4; nt++) {
            s[mt][nt] = (f32x4){0.f, 0.f, 0.f, 0.f};
            s[mt][nt] = __builtin_amdgcn_mfma_f32_16x16x32_bf16(qf, kf[nt], s[mt][nt], 0, 0, 0);
        }
    }

    const float SC = 0.25506953149031837f;   // (1/sqrt(32)) * log2(e)
    #pragma unroll
    for (int mt = 0; mt < 4; mt++) {
        #pragma unroll
        for (int rg = 0; rg < 4; rg++) {
            float v0 = s[mt][0][rg], v1 = s[mt][1][rg], v2 = s[mt][2][rg], v3 = s[mt][3][rg];
            float mx = fmaxf(fmaxf(v0, v1), fmaxf(v2, v3));
            #pragma unroll
            for (int msk = 1; msk < 16; msk <<= 1) mx = fmaxf(mx, __shfl_xor(mx, msk, 64));
            float e0 = exp2f((v0 - mx) * SC), e1 = exp2f((v1 - mx) * SC);
            float e2 = exp2f((v2 - mx) * SC), e3 = exp2f((v3 - mx) * SC);
            float sm = (e0 + e1) + (e2 + e3);
            #pragma unroll
            for (int msk = 1; msk < 16; msk <<= 1) sm += __shfl_xor(sm, msk, 64);
            float r = __builtin_amdgcn_rcpf(sm);
            int qt = mt * 16 + quad * 4 + rg;
            pt[h][qt][ 0 + l16] = f2bf(e0 * r);
            pt[h][qt][16 + l16] = f2bf(e1 * r);
            pt[h][qt][32 + l16] = f2bf(e2 * r);
            pt[h][qt][48 + l16] = f2bf(e3 * r);
        }
    }
    __syncthreads();   // drains all global loads; X2 stores are after this

    f32x4 o[4][2];
    #pragma unroll
    for (int mt = 0; mt < 4; mt++)
        #pragma unroll
        for (int nt = 0; nt < 2; nt++) o[mt][nt] = (f32x4){0.f, 0.f, 0.f, 0.f};
    #pragma unroll
    for (int ks = 0; ks < 2; ks++)
        #pragma unroll
        for (int mt = 0; mt < 4; mt++) {
            bf16x8 pf = *(const bf16x8*)&pt[h][mt * 16 + l16][ks * 32 + quad * 8];
            #pragma unroll
            for (int nt = 0; nt < 2; nt++)
                o[mt][nt] = __builtin_amdgcn_mfma_f32_16x16x32_bf16(pf, vf[ks][nt], o[mt][nt], 0, 0, 0);
        }

    // X2[t][c] bf16, c = h*32 + nt*16 + l16 (lane-contiguous 32B segments).
    ushort* x2 = qx2 + (size_t)win * 12288;
    #pragma unroll
    for (int mt = 0; mt < 4; mt++)
        #pragma unroll
        for (int nt = 0; nt < 2; nt++)
            #pragma unroll
            for (int rg = 0; rg < 4; rg++) {
                int qt = mt * 16 + quad * 4 + rg;
                x2[qt * CCH + h * 32 + nt * 16 + l16] = f2bf(o[mt][nt][rg]);
            }
}

extern "C" void kernel_launch(void* const* d_in, const int* in_sizes, int n_in,
                              void* d_out, int out_size, void* d_ws, size_t ws_size,
                              hipStream_t stream) {
    const float* x      = (const float*)d_in[0];
    const float* w_qkv  = (const float*)d_in[1];
    const float* b_qkv  = (const float*)d_in[2];
    const float* w_proj = (const float*)d_in[3];
    const float* b_proj = (const float*)d_in[4];
    float* out = (float*)d_out;
    ushort* ws = (ushort*)d_ws;

    ushort* X1 = (ushort*)d_out;   // 77 MB bf16 region inside d_out (154 MB)
    ushort* Q  = ws;               // [win][h][64][32] bf16; becomes X2 [win][t][c]
    ushort* K  = ws + QN;
    ushort* VT = ws + 2 * QN;      // [win][h][32][64] bf16 (ws total 231 MB)

    prep_x       <<<NWIN, 256, 0, stream>>>(x, X1);
    gemm_win<576><<<NTOK / 128, 256, 0, stream>>>(X1, w_qkv, b_qkv, Q, K, VT, nullptr);
    attn_win     <<<NWIN, 384, 0, stream>>>(Q, K, VT);
    gemm_win<192><<<NTOK / 128, 256, 0, stream>>>(Q, w_proj, b_proj, nullptr, nullptr, nullptr, out);
}